// Round 1
// baseline (183.785 us; speedup 1.0000x reference)
//
#include <hip/hip_runtime.h>
#include <hip/hip_bf16.h>
#include <stdint.h>

// Problem: B=32, C=256, H=W=32, 3x3 conv pad 1.
// Implicit GEMM: M = 32768 (b,h,w), N = 256 (co), K = 2304 (khkw,ci).
// k ordering: k = (kh*3+kw)*256 + ci  (consistent between A and B).

typedef short bf16x8 __attribute__((ext_vector_type(8)));
typedef float f32x4 __attribute__((ext_vector_type(4)));

__device__ __forceinline__ void gload_lds16(const void* g, const void* lds_byte_ptr) {
    // generic->AS1 and generic->AS3 via uintptr reinterpret (CK pattern).
    __builtin_amdgcn_global_load_lds(
        (const __attribute__((address_space(1))) unsigned int*)(uintptr_t)g,
        (__attribute__((address_space(3))) unsigned int*)(uintptr_t)lds_byte_ptr,
        16, 0, 0);
}

// weight (float [co][ci][3][3]) -> ternary bf16 [co][khkw][ci]  (589824 elems)
__global__ __launch_bounds__(256) void quant_w_kernel(const float* __restrict__ w,
                                                      __hip_bfloat16* __restrict__ wq) {
    int idx = blockIdx.x * 256 + threadIdx.x;     // output index
    int ci = idx & 255;
    int t = idx >> 8;
    int khkw = t % 9;
    int co = t / 9;
    float v = w[(co * 256 + ci) * 9 + khkw];
    float q = fminf(fmaxf(rintf(v), -1.f), 1.f);
    wq[idx] = __float2bfloat16(q);
}

// x (float NCHW) -> int-valued bf16, padded NHWC [b][34][34][ci] (zeros on border)
__global__ __launch_bounds__(256) void quant_x_kernel(const float* __restrict__ x,
                                                      __hip_bfloat16* __restrict__ xpad) {
    int idx = blockIdx.x * 256 + threadIdx.x;     // [b][hp][wp][ci]
    int ci = idx & 255;
    int t = idx >> 8;
    int wp = t % 34;
    t /= 34;
    int hp = t % 34;
    int b = t / 34;
    float q = 0.f;
    if (hp >= 1 && hp <= 32 && wp >= 1 && wp <= 32) {
        float v = x[((b * 256 + ci) * 32 + (hp - 1)) * 32 + (wp - 1)];
        q = fminf(fmaxf(rintf(__fmul_rn(v, 128.f)), -128.f), 127.f);
    }
    xpad[idx] = __float2bfloat16(q);   // integers <=128: exact in bf16
}

// 128x128 tile GEMM, BK=32, 4 waves 2x2, 4x4 16x16x32 bf16 MFMA frags per wave.
// Fused epilogue: y = acc*2^-7; y*inv + bias; q = clip(rint(2y),-2,1)*0.5.
__global__ __launch_bounds__(256) void conv_gemm_kernel(
    const __hip_bfloat16* __restrict__ xpad, const __hip_bfloat16* __restrict__ wq,
    const float* __restrict__ gamma, const float* __restrict__ beta,
    const float* __restrict__ mean, const float* __restrict__ var,
    float* __restrict__ out)
{
    __shared__ short As[128 * 32];  // [m_row][k] 64B rows
    __shared__ short Bs[128 * 32];  // [n_row][k]

    const int tid = threadIdx.x;
    const int wv = tid >> 6;
    const int lane = tid & 63;
    const int quad = lane >> 4;
    const int l16 = lane & 15;

    const int m0 = (blockIdx.x >> 1) * 128;
    const int n0 = (blockIdx.x & 1) * 128;
    const int wave_m = wv & 1;
    const int wave_n = wv >> 1;

    f32x4 acc[4][4];
#pragma unroll
    for (int i = 0; i < 4; i++)
#pragma unroll
        for (int j = 0; j < 4; j++) acc[i][j] = (f32x4){0.f, 0.f, 0.f, 0.f};

    for (int kt = 0; kt < 72; ++kt) {
        const int khkw = kt >> 3;           // 256/32 = 8 k-steps per (kh,kw)
        const int kh = khkw / 3;
        const int kw = khkw - 3 * kh;
        const int ci0 = (kt & 7) * 32;
        // ---- stage A,B tiles: 2 shots, 16B/lane, LDS dest = wave base + lane*16
#pragma unroll
        for (int s = 0; s < 2; ++s) {
            const int row = s * 64 + wv * 16 + (lane >> 2);
            const int cic = (lane & 3) * 8;
            const unsigned ldsOff = (unsigned)(s * 4096 + wv * 1024);
            // A: m-row -> (b,h,w); padded NHWC, no bounds checks needed
            const int m = m0 + row;
            const int b = m >> 10;
            const int h = (m >> 5) & 31;
            const int w = m & 31;
            const __hip_bfloat16* ga =
                xpad + (size_t)(((b * 34 + h + kh) * 34) + (w + kw)) * 256 + ci0 + cic;
            gload_lds16(ga, (const char*)As + ldsOff);
            // B: n-row (co), row-major [co][k]
            const __hip_bfloat16* gb = wq + (size_t)(n0 + row) * 2304 + kt * 32 + cic;
            gload_lds16(gb, (const char*)Bs + ldsOff);
        }
        __syncthreads();   // drains vmcnt before barrier -> LDS valid

        bf16x8 af[4], bfr[4];
#pragma unroll
        for (int i = 0; i < 4; i++) {
            const int row = wave_m * 64 + i * 16 + l16;
            af[i] = *(const bf16x8*)(&As[row * 32 + quad * 8]);   // ds_read_b128
        }
#pragma unroll
        for (int j = 0; j < 4; j++) {
            const int row = wave_n * 64 + j * 16 + l16;
            bfr[j] = *(const bf16x8*)(&Bs[row * 32 + quad * 8]);
        }
#pragma unroll
        for (int i = 0; i < 4; i++)
#pragma unroll
            for (int j = 0; j < 4; j++)
                acc[i][j] = __builtin_amdgcn_mfma_f32_16x16x32_bf16(af[i], bfr[j], acc[i][j], 0, 0, 0);
        __syncthreads();   // protect LDS from next iteration's staging
    }

    // ---- epilogue: C/D layout col = lane&15 (n), row = quad*4 + reg (m)
#pragma unroll
    for (int j = 0; j < 4; j++) {
        const int co = n0 + wave_n * 64 + j * 16 + l16;
        const float iv = __fdiv_rn(gamma[co], __fsqrt_rn(__fadd_rn(var[co], 1e-4f)));
        const float bias = __fsub_rn(beta[co], __fmul_rn(mean[co], iv));
#pragma unroll
        for (int i = 0; i < 4; i++) {
            const int m_base = m0 + wave_m * 64 + i * 16 + quad * 4;  // 4 consecutive m = same h, w..w+3
            const int b = m_base >> 10;
            const int h = (m_base >> 5) & 31;
            const int w = m_base & 31;
            f32x4 v;
#pragma unroll
            for (int r = 0; r < 4; r++) {
                const float y = __fmul_rn(acc[i][j][r], 0.0078125f);  // exact pow2 scale
                const float t = __fadd_rn(__fmul_rn(y, iv), bias);    // no FMA: match np
                float z = rintf(__fmul_rn(t, 2.f));                    // half-to-even
                z = fminf(fmaxf(z, -2.f), 1.f);
                v[r] = __fmul_rn(z, 0.5f);
            }
            *(f32x4*)(&out[(((size_t)(b * 256 + co)) * 32 + h) * 32 + w]) = v;  // 16B store
        }
    }
}

extern "C" void kernel_launch(void* const* d_in, const int* in_sizes, int n_in,
                              void* d_out, int out_size, void* d_ws, size_t ws_size,
                              hipStream_t stream) {
    const float* x      = (const float*)d_in[0];
    const float* weight = (const float*)d_in[1];
    const float* gamma  = (const float*)d_in[2];
    const float* beta   = (const float*)d_in[3];
    const float* rmean  = (const float*)d_in[4];
    const float* rvar   = (const float*)d_in[5];
    float* out = (float*)d_out;

    // workspace layout
    __hip_bfloat16* wq   = (__hip_bfloat16*)d_ws;                       // 589824 * 2 B
    __hip_bfloat16* xpad = (__hip_bfloat16*)((char*)d_ws + 1179648);    // 32*34*34*256 * 2 B

    quant_w_kernel<<<2304, 256, 0, stream>>>(weight, wq);
    quant_x_kernel<<<36992, 256, 0, stream>>>(x, xpad);
    conv_gemm_kernel<<<512, 256, 0, stream>>>(xpad, wq, gamma, beta, rmean, rvar, out);
}

// Round 2
// 126.766 us; speedup vs baseline: 1.4498x; 1.4498x over previous
//
#include <hip/hip_runtime.h>
#include <hip/hip_bf16.h>
#include <stdint.h>

// Problem: B=32, C=256, H=W=32, 3x3 conv pad 1.
// Implicit GEMM in INT8: M = 32768 (b,h,w), N = 256 (co), K = 2304 (khkw,ci).
// x quant -> integers in [-128,127] (exact int8); weights ternary {-1,0,1}.
// i32 accumulation is exact; (float)acc exact (|acc| <= 294912 < 2^24), so
// numerics are bit-identical to the fp path. k = (kh*3+kw)*256 + ci.

typedef int i32x4 __attribute__((ext_vector_type(4)));
typedef float f32x4 __attribute__((ext_vector_type(4)));

__device__ __forceinline__ void gload_lds16(const void* g, const void* lds_byte_ptr) {
    __builtin_amdgcn_global_load_lds(
        (const __attribute__((address_space(1))) unsigned int*)(uintptr_t)g,
        (__attribute__((address_space(3))) unsigned int*)(uintptr_t)lds_byte_ptr,
        16, 0, 0);
}

// weight (float [co][ci][3][3]) -> ternary int8 [co][khkw][ci].
// One block per co: coalesced read of 2304 floats, LDS transpose, coalesced 16B writes.
__global__ __launch_bounds__(256) void quant_w_kernel(const float* __restrict__ w,
                                                      signed char* __restrict__ wq) {
    __shared__ signed char tile[2304];
    const int co = blockIdx.x;
    const int t = threadIdx.x;
#pragma unroll
    for (int p = 0; p < 9; ++p) {
        const int idx = p * 256 + t;          // (ci, khkw) flattened, khkw fastest
        const float v = w[co * 2304 + idx];
        const int ci = idx / 9;
        const int khkw = idx - 9 * ci;
        const float q = fminf(fmaxf(rintf(v), -1.f), 1.f);
        tile[khkw * 256 + ci] = (signed char)(int)q;
    }
    __syncthreads();
    if (t < 144) {
        *(uint4*)(wq + (size_t)co * 2304 + t * 16) = *(const uint4*)(tile + t * 16);
    }
}

// x (float NCHW) -> int8, padded NHWC [b][34][34][ci]; interior only
// (border pre-zeroed by memset). One block per (b,h) row; LDS transpose.
__global__ __launch_bounds__(256) void quant_x_kernel(const float* __restrict__ x,
                                                      signed char* __restrict__ xpad) {
    __shared__ signed char tile[32 * 272];   // [w][ci], stride 272 (16B-aligned rows)
    const int t = threadIdx.x;
    const int b = blockIdx.x >> 5;
    const int h = blockIdx.x & 31;
    const int w = t & 31;
    const int cg = (t >> 5) * 4;             // 4-channel group base within a pass
#pragma unroll
    for (int p = 0; p < 8; ++p) {
        const int ci = p * 32 + cg;
        unsigned packed = 0;
#pragma unroll
        for (int k = 0; k < 4; ++k) {
            // coalesced: for fixed (ci+k), 32 lanes read 128B contiguous
            const float v = x[(((size_t)(b * 256 + ci + k)) * 32 + h) * 32 + w];
            float q = fminf(fmaxf(rintf(__fmul_rn(v, 128.f)), -128.f), 127.f);
            packed |= ((unsigned)(unsigned char)(signed char)(int)q) << (8 * k);
        }
        *(unsigned*)(tile + w * 272 + ci) = packed;
    }
    __syncthreads();
    // write out: 2 passes, 16B per lane, fully coalesced (4KB contiguous / pass)
#pragma unroll
    for (int q = 0; q < 2; ++q) {
        const int wp = q * 16 + (t >> 4);    // 0..31
        const int ci16 = (t & 15) * 16;
        uint4 v = *(const uint4*)(tile + wp * 272 + ci16);
        *(uint4*)(xpad + (size_t)(((b * 34 + h + 1) * 34) + (wp + 1)) * 256 + ci16) = v;
    }
}

// 128x128 tile GEMM, BK=64 (int8), 4 waves 2x2, 4x4 16x16x64 i8 MFMA frags/wave.
// Fused epilogue: y = (float)acc * 2^-7; y*inv + bias; q = clip(rint(2y),-2,1)*0.5.
__global__ __launch_bounds__(256) void conv_gemm_kernel(
    const signed char* __restrict__ xpad, const signed char* __restrict__ wq,
    const float* __restrict__ gamma, const float* __restrict__ beta,
    const float* __restrict__ mean, const float* __restrict__ var,
    float* __restrict__ out)
{
    __shared__ signed char As[128 * 64];  // [m_row][k] 64B rows
    __shared__ signed char Bs[128 * 64];  // [n_row][k]

    const int tid = threadIdx.x;
    const int wv = tid >> 6;
    const int lane = tid & 63;
    const int quad = lane >> 4;
    const int l16 = lane & 15;

    const int m0 = (blockIdx.x >> 1) * 128;
    const int n0 = (blockIdx.x & 1) * 128;
    const int wave_m = wv & 1;
    const int wave_n = wv >> 1;

    i32x4 acc[4][4];
#pragma unroll
    for (int i = 0; i < 4; i++)
#pragma unroll
        for (int j = 0; j < 4; j++) acc[i][j] = (i32x4){0, 0, 0, 0};

    for (int kt = 0; kt < 36; ++kt) {
        const int khkw = kt >> 2;            // 256/64 = 4 k-steps per (kh,kw)
        const int kh = khkw / 3;
        const int kw = khkw - 3 * kh;
        const int ci0 = (kt & 3) * 64;
#pragma unroll
        for (int s = 0; s < 2; ++s) {
            const int row = s * 64 + wv * 16 + (lane >> 2);
            const int cic = (lane & 3) * 16;
            const unsigned ldsOff = (unsigned)(s * 4096 + wv * 1024);
            const int m = m0 + row;
            const int b = m >> 10;
            const int h = (m >> 5) & 31;
            const int w = m & 31;
            const signed char* ga =
                xpad + (size_t)(((b * 34 + h + kh) * 34) + (w + kw)) * 256 + ci0 + cic;
            gload_lds16(ga, As + ldsOff);
            const signed char* gb = wq + (size_t)(n0 + row) * 2304 + kt * 64 + cic;
            gload_lds16(gb, Bs + ldsOff);
        }
        __syncthreads();

        i32x4 af[4], bfr[4];
#pragma unroll
        for (int i = 0; i < 4; i++) {
            const int row = wave_m * 64 + i * 16 + l16;
            af[i] = *(const i32x4*)(As + row * 64 + quad * 16);   // ds_read_b128
        }
#pragma unroll
        for (int j = 0; j < 4; j++) {
            const int row = wave_n * 64 + j * 16 + l16;
            bfr[j] = *(const i32x4*)(Bs + row * 64 + quad * 16);
        }
#pragma unroll
        for (int i = 0; i < 4; i++)
#pragma unroll
            for (int j = 0; j < 4; j++)
                acc[i][j] = __builtin_amdgcn_mfma_i32_16x16x64_i8(af[i], bfr[j], acc[i][j], 0, 0, 0);
        __syncthreads();
    }

    // epilogue: C/D layout col = lane&15 (n), row = quad*4 + reg (m)
#pragma unroll
    for (int j = 0; j < 4; j++) {
        const int co = n0 + wave_n * 64 + j * 16 + l16;
        const float iv = __fdiv_rn(gamma[co], __fsqrt_rn(__fadd_rn(var[co], 1e-4f)));
        const float bias = __fsub_rn(beta[co], __fmul_rn(mean[co], iv));
#pragma unroll
        for (int i = 0; i < 4; i++) {
            const int m_base = m0 + wave_m * 64 + i * 16 + quad * 4;
            const int b = m_base >> 10;
            const int h = (m_base >> 5) & 31;
            const int w = m_base & 31;
            f32x4 v;
#pragma unroll
            for (int r = 0; r < 4; r++) {
                const float y = __fmul_rn((float)acc[i][j][r], 0.0078125f);  // exact
                const float t = __fadd_rn(__fmul_rn(y, iv), bias);           // no FMA
                float z = rintf(__fmul_rn(t, 2.f));
                z = fminf(fmaxf(z, -2.f), 1.f);
                v[r] = __fmul_rn(z, 0.5f);
            }
            *(f32x4*)(&out[(((size_t)(b * 256 + co)) * 32 + h) * 32 + w]) = v;
        }
    }
}

extern "C" void kernel_launch(void* const* d_in, const int* in_sizes, int n_in,
                              void* d_out, int out_size, void* d_ws, size_t ws_size,
                              hipStream_t stream) {
    const float* x      = (const float*)d_in[0];
    const float* weight = (const float*)d_in[1];
    const float* gamma  = (const float*)d_in[2];
    const float* beta   = (const float*)d_in[3];
    const float* rmean  = (const float*)d_in[4];
    const float* rvar   = (const float*)d_in[5];
    float* out = (float*)d_out;

    signed char* wq   = (signed char*)d_ws;                         // 589,824 B
    signed char* xpad = (signed char*)d_ws + (1 << 20);             // 32*34*34*256 = 9,469,952 B

    quant_w_kernel<<<256, 256, 0, stream>>>(weight, wq);
    hipMemsetAsync(xpad, 0, (size_t)32 * 34 * 34 * 256, stream);    // border zeros
    quant_x_kernel<<<1024, 256, 0, stream>>>(x, xpad);
    conv_gemm_kernel<<<512, 256, 0, stream>>>(xpad, wq, gamma, beta, rmean, rvar, out);
}

// Round 3
// 123.478 us; speedup vs baseline: 1.4884x; 1.0266x over previous
//
#include <hip/hip_runtime.h>
#include <hip/hip_bf16.h>
#include <stdint.h>

// Problem: B=32, C=256, H=W=32, 3x3 conv pad 1.
// Implicit GEMM in INT8: M = 32768 (b,h,w), N = 256 (co), K = 2304 (khkw,ci).
// x quant -> integers in [-128,127] (exact int8); weights ternary {-1,0,1}.
// i32 accumulation exact; (float)acc exact (|acc| <= 294912 < 2^24).
// k = (kh*3+kw)*256 + ci.

typedef int i32x4 __attribute__((ext_vector_type(4)));
typedef float f32x4 __attribute__((ext_vector_type(4)));

__device__ __forceinline__ void gload_lds16(const void* g, const void* lds_byte_ptr) {
    __builtin_amdgcn_global_load_lds(
        (const __attribute__((address_space(1))) unsigned int*)(uintptr_t)g,
        (__attribute__((address_space(3))) unsigned int*)(uintptr_t)lds_byte_ptr,
        16, 0, 0);
}

// weight (float [co][ci][3][3]) -> ternary int8 [co][khkw][ci].
__global__ __launch_bounds__(256) void quant_w_kernel(const float* __restrict__ w,
                                                      signed char* __restrict__ wq) {
    __shared__ signed char tile[2304];
    const int co = blockIdx.x;
    const int t = threadIdx.x;
#pragma unroll
    for (int p = 0; p < 9; ++p) {
        const int idx = p * 256 + t;
        const float v = w[co * 2304 + idx];
        const int ci = idx / 9;
        const int khkw = idx - 9 * ci;
        const float q = fminf(fmaxf(rintf(v), -1.f), 1.f);
        tile[khkw * 256 + ci] = (signed char)(int)q;
    }
    __syncthreads();
    if (t < 144) {
        *(uint4*)(wq + (size_t)co * 2304 + t * 16) = *(const uint4*)(tile + t * 16);
    }
}

// x (float NCHW) -> int8, padded NHWC [b][34][34][ci]; writes the WHOLE padded
// buffer including zero borders (no memset needed). One block per (b, hp) row.
__global__ __launch_bounds__(256) void quant_x_kernel(const float* __restrict__ x,
                                                      signed char* __restrict__ xpad) {
    __shared__ signed char tile[32 * 272];   // [w][ci], stride 272
    const int t = threadIdx.x;
    const int b = blockIdx.x / 34;
    const int hp = blockIdx.x % 34;
    signed char* rowbase = xpad + (size_t)((b * 34 + hp) * 34) * 256;
    const uint4 z = {0u, 0u, 0u, 0u};
    if (hp == 0 || hp == 33) {               // whole padded row = zeros (8704 B)
        for (int i = t; i < 544; i += 256) *(uint4*)(rowbase + i * 16) = z;
        return;                               // uniform per block: barrier-safe
    }
    const int h = hp - 1;
    const int w = t & 31;
    const int cg = (t >> 5) * 4;
#pragma unroll
    for (int p = 0; p < 8; ++p) {
        const int ci = p * 32 + cg;
        unsigned packed = 0;
#pragma unroll
        for (int k = 0; k < 4; ++k) {
            // coalesced: for fixed (ci+k), 32 lanes read 128B contiguous
            const float v = x[(((size_t)(b * 256 + ci + k)) * 32 + h) * 32 + w];
            float q = fminf(fmaxf(rintf(__fmul_rn(v, 128.f)), -128.f), 127.f);
            packed |= ((unsigned)(unsigned char)(signed char)(int)q) << (8 * k);
        }
        *(unsigned*)(tile + w * 272 + ci) = packed;
    }
    __syncthreads();
#pragma unroll
    for (int q = 0; q < 2; ++q) {            // interior: 16B/lane, coalesced
        const int wp = q * 16 + (t >> 4);
        const int ci16 = (t & 15) * 16;
        uint4 v = *(const uint4*)(tile + wp * 272 + ci16);
        *(uint4*)(rowbase + (size_t)(wp + 1) * 256 + ci16) = v;
    }
    if (t < 32) {                            // zero border columns wp=0 and wp=33
        const int wp = (t >> 4) * 33;
        *(uint4*)(rowbase + (size_t)wp * 256 + (t & 15) * 16) = z;
    }
}

// 128x128 tile GEMM, BK=64 int8, 512 threads = 8 waves (2x4 wave grid),
// 4x2 frags of 16x16x64 per wave. 2 blocks/CU -> 16 waves/CU.
__global__ __launch_bounds__(512) void conv_gemm_kernel(
    const signed char* __restrict__ xpad, const signed char* __restrict__ wq,
    const float* __restrict__ gamma, const float* __restrict__ beta,
    const float* __restrict__ mean, const float* __restrict__ var,
    float* __restrict__ out)
{
    __shared__ signed char As[128 * 64];  // [m_row][k] 64B rows
    __shared__ signed char Bs[128 * 64];  // [n_row][k]

    const int tid = threadIdx.x;
    const int wv = tid >> 6;              // 0..7
    const int lane = tid & 63;
    const int quad = lane >> 4;
    const int l16 = lane & 15;

    const int m0 = (blockIdx.x >> 1) * 128;
    const int n0 = (blockIdx.x & 1) * 128;
    const int wave_m = wv & 1;            // 2 waves over m (64 each)
    const int wave_n = wv >> 1;           // 4 waves over n (32 each)

    i32x4 acc[4][2];
#pragma unroll
    for (int i = 0; i < 4; i++)
#pragma unroll
        for (int j = 0; j < 2; j++) acc[i][j] = (i32x4){0, 0, 0, 0};

    // staging indices: one 16B shot per thread per tile (512 x 16B = 8KB)
    const int srow = tid >> 2;            // 0..127
    const int scic = (tid & 3) * 16;
    const unsigned ldsOff = (unsigned)(wv * 1024);  // wave base; HW adds lane*16
    const int sb = (m0 + srow) >> 10;
    const int sh = ((m0 + srow) >> 5) & 31;
    const int sw = (m0 + srow) & 31;

    for (int kt = 0; kt < 36; ++kt) {
        const int khkw = kt >> 2;
        const int kh = khkw / 3;
        const int kw = khkw - 3 * kh;
        const int ci0 = (kt & 3) * 64;
        const signed char* ga =
            xpad + (size_t)(((sb * 34 + sh + kh) * 34) + (sw + kw)) * 256 + ci0 + scic;
        gload_lds16(ga, As + ldsOff);
        const signed char* gb = wq + (size_t)(n0 + srow) * 2304 + kt * 64 + scic;
        gload_lds16(gb, Bs + ldsOff);
        __syncthreads();

        i32x4 af[4], bfr[2];
#pragma unroll
        for (int i = 0; i < 4; i++) {
            const int row = wave_m * 64 + i * 16 + l16;
            af[i] = *(const i32x4*)(As + row * 64 + quad * 16);   // ds_read_b128
        }
#pragma unroll
        for (int j = 0; j < 2; j++) {
            const int row = wave_n * 32 + j * 16 + l16;
            bfr[j] = *(const i32x4*)(Bs + row * 64 + quad * 16);
        }
#pragma unroll
        for (int i = 0; i < 4; i++)
#pragma unroll
            for (int j = 0; j < 2; j++)
                acc[i][j] = __builtin_amdgcn_mfma_i32_16x16x64_i8(af[i], bfr[j], acc[i][j], 0, 0, 0);
        __syncthreads();
    }

    // epilogue: C/D layout col = lane&15 (n), row = quad*4 + reg (m)
#pragma unroll
    for (int j = 0; j < 2; j++) {
        const int co = n0 + wave_n * 32 + j * 16 + l16;
        const float iv = __fdiv_rn(gamma[co], __fsqrt_rn(__fadd_rn(var[co], 1e-4f)));
        const float bias = __fsub_rn(beta[co], __fmul_rn(mean[co], iv));
#pragma unroll
        for (int i = 0; i < 4; i++) {
            const int m_base = m0 + wave_m * 64 + i * 16 + quad * 4;
            const int b = m_base >> 10;
            const int h = (m_base >> 5) & 31;
            const int w = m_base & 31;
            f32x4 v;
#pragma unroll
            for (int r = 0; r < 4; r++) {
                const float y = __fmul_rn((float)acc[i][j][r], 0.0078125f);  // exact
                const float t = __fadd_rn(__fmul_rn(y, iv), bias);           // no FMA
                float z = rintf(__fmul_rn(t, 2.f));
                z = fminf(fmaxf(z, -2.f), 1.f);
                v[r] = __fmul_rn(z, 0.5f);
            }
            *(f32x4*)(&out[(((size_t)(b * 256 + co)) * 32 + h) * 32 + w]) = v;
        }
    }
}

extern "C" void kernel_launch(void* const* d_in, const int* in_sizes, int n_in,
                              void* d_out, int out_size, void* d_ws, size_t ws_size,
                              hipStream_t stream) {
    const float* x      = (const float*)d_in[0];
    const float* weight = (const float*)d_in[1];
    const float* gamma  = (const float*)d_in[2];
    const float* beta   = (const float*)d_in[3];
    const float* rmean  = (const float*)d_in[4];
    const float* rvar   = (const float*)d_in[5];
    float* out = (float*)d_out;

    signed char* wq   = (signed char*)d_ws;                 // 589,824 B
    signed char* xpad = (signed char*)d_ws + (1 << 20);     // 32*34*34*256 = 9,469,952 B

    quant_w_kernel<<<256, 256, 0, stream>>>(weight, wq);
    quant_x_kernel<<<1088, 256, 0, stream>>>(x, xpad);      // writes borders too
    conv_gemm_kernel<<<512, 512, 0, stream>>>(xpad, wq, gamma, beta, rmean, rvar, out);
}

// Round 4
// 118.169 us; speedup vs baseline: 1.5553x; 1.0449x over previous
//
#include <hip/hip_runtime.h>
#include <hip/hip_bf16.h>
#include <stdint.h>

// B=32, C=256, H=W=32, 3x3 conv pad 1 -> implicit GEMM in INT8.
// M = 32768 (b,h,w), N = 256 (co), K = 2304; k = (kh*3+kw)*256 + ci.
// Restructured K-loop: A staged ONCE per block (52KB halo, 1 barrier total),
// B read per-fragment from L2 in precomputed MFMA layout (no LDS, no barriers).

typedef int i32x4 __attribute__((ext_vector_type(4)));
typedef float f32x4 __attribute__((ext_vector_type(4)));

__device__ __forceinline__ void gload_lds16(const void* g, const void* lds) {
    __builtin_amdgcn_global_load_lds(
        (const __attribute__((address_space(1))) unsigned int*)(uintptr_t)g,
        (__attribute__((address_space(3))) unsigned int*)(uintptr_t)lds,
        16, 0, 0);
}

// weight (float [co][ci][3][3]) -> ternary int8 in MFMA-fragment order:
// B'[(co>>4)][kt 0..35][kq 0..3][co&15][j 0..15], elem = Wq[co][k=kt*64+kq*16+j].
__global__ __launch_bounds__(256) void quant_w_kernel(const float* __restrict__ w,
                                                      signed char* __restrict__ wq) {
    __shared__ signed char tile[2304];    // k-ordered: [khkw*256 + ci]
    const int co = blockIdx.x;
    const int t = threadIdx.x;
#pragma unroll
    for (int p = 0; p < 9; ++p) {
        const int idx = p * 256 + t;                 // = ci*9 + khkw
        const float v = w[co * 2304 + idx];
        const int ci = idx / 9;
        const int khkw = idx - 9 * ci;
        const float q = fminf(fmaxf(rintf(v), -1.f), 1.f);
        tile[khkw * 256 + ci] = (signed char)(int)q;
    }
    __syncthreads();
    if (t < 144) {                                   // t = kt*4 + kq
        const int kt = t >> 2, kq = t & 3;
        const uint4 v = *(const uint4*)(tile + t * 16);   // tile[kt*64+kq*16 ..]
        *(uint4*)(wq + ((size_t)((co >> 4) * 36 + kt) << 10) + kq * 256 + (co & 15) * 16) = v;
    }
}

// x (float NCHW) -> int8, padded NHWC [b][34][34][ci], borders zeroed.
__global__ __launch_bounds__(256) void quant_x_kernel(const float* __restrict__ x,
                                                      signed char* __restrict__ xpad) {
    __shared__ signed char tile[32 * 272];
    const int t = threadIdx.x;
    const int b = blockIdx.x / 34;
    const int hp = blockIdx.x % 34;
    signed char* rowbase = xpad + (size_t)((b * 34 + hp) * 34) * 256;
    const uint4 z = {0u, 0u, 0u, 0u};
    if (hp == 0 || hp == 33) {
        for (int i = t; i < 544; i += 256) *(uint4*)(rowbase + i * 16) = z;
        return;
    }
    const int h = hp - 1;
    const int w = t & 31;
    const int cg = (t >> 5) * 4;
#pragma unroll
    for (int p = 0; p < 8; ++p) {
        const int ci = p * 32 + cg;
        unsigned packed = 0;
#pragma unroll
        for (int k = 0; k < 4; ++k) {
            const float v = x[(((size_t)(b * 256 + ci + k)) * 32 + h) * 32 + w];
            float q = fminf(fmaxf(rintf(__fmul_rn(v, 128.f)), -128.f), 127.f);
            packed |= ((unsigned)(unsigned char)(signed char)(int)q) << (8 * k);
        }
        *(unsigned*)(tile + w * 272 + ci) = packed;
    }
    __syncthreads();
#pragma unroll
    for (int q = 0; q < 2; ++q) {
        const int wp = q * 16 + (t >> 4);
        const int ci16 = (t & 15) * 16;
        uint4 v = *(const uint4*)(tile + wp * 272 + ci16);
        *(uint4*)(rowbase + (size_t)(wp + 1) * 256 + ci16) = v;
    }
    if (t < 32) {
        const int wp = (t >> 4) * 33;
        *(uint4*)(rowbase + (size_t)wp * 256 + (t & 15) * 16) = z;
    }
}

// GEMM: grid 512 (256 m-tiles x 2 n-tiles), 512 threads = 8 waves (2m x 4n).
// Wave = 64m x 32n: 4 m-frags x 2 n-frags of 16x16x64 i8, acc 32 VGPRs.
// LDS: A halo only, 6 rows x 34 wp x 256 ci = 52,224 B, xor-swizzled chunks.
__global__ __launch_bounds__(512, 4) void conv_gemm_kernel(
    const signed char* __restrict__ xpad, const signed char* __restrict__ wqm,
    const float* __restrict__ gamma, const float* __restrict__ beta,
    const float* __restrict__ mean, const float* __restrict__ var,
    float* __restrict__ out)
{
    __shared__ signed char As[6 * 34 * 256];   // [r=hh*34+wp][chunk^ (r&15)][16]

    const int tid = threadIdx.x;
    const int wv = tid >> 6;
    const int lane = tid & 63;
    const int l16 = lane & 15;
    const int l4 = lane >> 4;

    const int mt = blockIdx.x >> 1;
    const int n0 = (blockIdx.x & 1) * 128;
    const int b = mt >> 3;
    const int h0 = (mt & 7) * 4;
    const int wave_m = wv & 1;    // 2 waves over m (64 each)
    const int wave_n = wv >> 1;   // 4 waves over n (32 each)

    // ---- stage A halo once: padded rows h0..h0+5, all 34 wp, all 256 ci ----
    const signed char* xbase = xpad + (size_t)(b * 34 + h0) * 34 * 256;
    for (int i = wv; i < 51; i += 8) {           // 51 wave-instrs x 1KB = 52,224B
        const int d = i * 64 + lane;             // dest chunk 0..3263
        const int r = d >> 4;
        const int c = d & 15;
        gload_lds16(xbase + r * 256 + ((c ^ (r & 15)) << 4), As + i * 1024);
    }
    __syncthreads();   // the ONLY barrier

    // per-frag loop-invariant A row bases: frag i -> h = h0+wave_m*2+(i>>1), w = (i&1)*16 + l16
    int r0[4];
#pragma unroll
    for (int i = 0; i < 4; ++i)
        r0[i] = (wave_m * 2 + (i >> 1)) * 34 + (i & 1) * 16 + l16;

    // B frag pointers (L2-hot, MFMA layout): frag j -> co_blk = n0/16 + wave_n*2 + j
    const signed char* bp0 = wqm + (((size_t)((n0 >> 4) + wave_n * 2 + 0) * 36) << 10) + lane * 16;
    const signed char* bp1 = wqm + (((size_t)((n0 >> 4) + wave_n * 2 + 1) * 36) << 10) + lane * 16;

    i32x4 acc[4][2];
#pragma unroll
    for (int i = 0; i < 4; i++)
#pragma unroll
        for (int j = 0; j < 2; j++) acc[i][j] = (i32x4){0, 0, 0, 0};

    i32x4 aA[4], bA[2], aB[4], bB[2];

#define LOAD_B(kt, dst) { dst[0] = *(const i32x4*)(bp0 + (kt) * 1024); \
                          dst[1] = *(const i32x4*)(bp1 + (kt) * 1024); }
#define LOAD_A(kt, dst) { const int khkw = (kt) >> 2; \
                          const int kh = khkw / 3; \
                          const int kw = khkw - 3 * kh; \
                          const int roff = kh * 34 + kw; \
                          const int cb = ((kt) & 3) * 4 + l4; \
                          _Pragma("unroll") \
                          for (int i = 0; i < 4; ++i) { \
                              const int r = r0[i] + roff; \
                              dst[i] = *(const i32x4*)(As + r * 256 + ((cb ^ (r & 15)) << 4)); \
                          } }
#define MFMA(af, bf) { _Pragma("unroll") \
                       for (int i = 0; i < 4; ++i) \
                           _Pragma("unroll") \
                           for (int j = 0; j < 2; ++j) \
                               acc[i][j] = __builtin_amdgcn_mfma_i32_16x16x64_i8(af[i], bf[j], acc[i][j], 0, 0, 0); }

    LOAD_B(0, bA)
    LOAD_A(0, aA)
    for (int kt = 0; kt < 36; kt += 2) {         // ping-pong, no barriers
        LOAD_B(kt + 1, bB)
        LOAD_A(kt + 1, aB)
        MFMA(aA, bA)
        if (kt + 2 < 36) { LOAD_B(kt + 2, bA) LOAD_A(kt + 2, aA) }
        MFMA(aB, bB)
    }

    // ---- epilogue: C/D col = l16 (n), row = l4*4 + r (m within frag) ----
#pragma unroll
    for (int j = 0; j < 2; ++j) {
        const int co = n0 + wave_n * 32 + j * 16 + l16;
        const float iv = __fdiv_rn(gamma[co], __fsqrt_rn(__fadd_rn(var[co], 1e-4f)));
        const float bias = __fsub_rn(beta[co], __fmul_rn(mean[co], iv));
#pragma unroll
        for (int i = 0; i < 4; ++i) {
            const int h = h0 + wave_m * 2 + (i >> 1);
            const int w = (i & 1) * 16 + l4 * 4;
            f32x4 v;
#pragma unroll
            for (int r = 0; r < 4; r++) {
                const float y = __fmul_rn((float)acc[i][j][r], 0.0078125f);  // exact pow2
                const float t = __fadd_rn(__fmul_rn(y, iv), bias);           // no FMA: match np
                float z = rintf(__fmul_rn(t, 2.f));
                z = fminf(fmaxf(z, -2.f), 1.f);
                v[r] = __fmul_rn(z, 0.5f);
            }
            *(f32x4*)(&out[(((size_t)(b * 256 + co)) * 32 + h) * 32 + w]) = v;
        }
    }
#undef LOAD_B
#undef LOAD_A
#undef MFMA
}

extern "C" void kernel_launch(void* const* d_in, const int* in_sizes, int n_in,
                              void* d_out, int out_size, void* d_ws, size_t ws_size,
                              hipStream_t stream) {
    const float* x      = (const float*)d_in[0];
    const float* weight = (const float*)d_in[1];
    const float* gamma  = (const float*)d_in[2];
    const float* beta   = (const float*)d_in[3];
    const float* rmean  = (const float*)d_in[4];
    const float* rvar   = (const float*)d_in[5];
    float* out = (float*)d_out;

    signed char* wq   = (signed char*)d_ws;                 // 589,824 B (MFMA layout)
    signed char* xpad = (signed char*)d_ws + (1 << 20);     // 9,469,952 B

    quant_w_kernel<<<256, 256, 0, stream>>>(weight, wq);
    quant_x_kernel<<<1088, 256, 0, stream>>>(x, xpad);
    conv_gemm_kernel<<<512, 512, 0, stream>>>(xpad, wq, gamma, beta, rmean, rvar, out);
}

// Round 5
// 118.105 us; speedup vs baseline: 1.5561x; 1.0005x over previous
//
#include <hip/hip_runtime.h>
#include <hip/hip_bf16.h>
#include <stdint.h>

// B=32, C=256, H=W=32, 3x3 conv pad 1 -> implicit GEMM in INT8.
// M = 32768 (b,h,w), N = 256 (co), K = 2304; k = (kh*3+kw)*256 + ci.
// A staged ONCE per block (52KB halo in LDS, 1 barrier total); B read
// per-fragment from L2 in precomputed MFMA layout. K-loop FULLY UNROLLED
// (36 steps): all addresses const-fold; depth-2 register ping-pong.

typedef int i32x4 __attribute__((ext_vector_type(4)));
typedef float f32x4 __attribute__((ext_vector_type(4)));

__device__ __forceinline__ void gload_lds16(const void* g, const void* lds) {
    __builtin_amdgcn_global_load_lds(
        (const __attribute__((address_space(1))) unsigned int*)(uintptr_t)g,
        (__attribute__((address_space(3))) unsigned int*)(uintptr_t)lds,
        16, 0, 0);
}

// weight (float [co][ci][3][3]) -> ternary int8 in MFMA-fragment order:
// B'[(co>>4)][kt 0..35][kq 0..3][co&15][j 0..15], elem = Wq[co][k=kt*64+kq*16+j].
__global__ __launch_bounds__(256) void quant_w_kernel(const float* __restrict__ w,
                                                      signed char* __restrict__ wq) {
    __shared__ signed char tile[2304];    // k-ordered: [khkw*256 + ci]
    const int co = blockIdx.x;
    const int t = threadIdx.x;
#pragma unroll
    for (int p = 0; p < 9; ++p) {
        const int idx = p * 256 + t;                 // = ci*9 + khkw
        const float v = w[co * 2304 + idx];
        const int ci = idx / 9;
        const int khkw = idx - 9 * ci;
        const float q = fminf(fmaxf(rintf(v), -1.f), 1.f);
        tile[khkw * 256 + ci] = (signed char)(int)q;
    }
    __syncthreads();
    if (t < 144) {                                   // t = kt*4 + kq
        const int kt = t >> 2, kq = t & 3;
        const uint4 v = *(const uint4*)(tile + t * 16);
        *(uint4*)(wq + ((size_t)((co >> 4) * 36 + kt) << 10) + kq * 256 + (co & 15) * 16) = v;
    }
}

// x (float NCHW) -> int8, padded NHWC [b][34][34][ci], borders zeroed.
__global__ __launch_bounds__(256) void quant_x_kernel(const float* __restrict__ x,
                                                      signed char* __restrict__ xpad) {
    __shared__ signed char tile[32 * 272];
    const int t = threadIdx.x;
    const int b = blockIdx.x / 34;
    const int hp = blockIdx.x % 34;
    signed char* rowbase = xpad + (size_t)((b * 34 + hp) * 34) * 256;
    const uint4 z = {0u, 0u, 0u, 0u};
    if (hp == 0 || hp == 33) {
        for (int i = t; i < 544; i += 256) *(uint4*)(rowbase + i * 16) = z;
        return;
    }
    const int h = hp - 1;
    const int w = t & 31;
    const int cg = (t >> 5) * 4;
#pragma unroll
    for (int p = 0; p < 8; ++p) {
        const int ci = p * 32 + cg;
        unsigned packed = 0;
#pragma unroll
        for (int k = 0; k < 4; ++k) {
            const float v = x[(((size_t)(b * 256 + ci + k)) * 32 + h) * 32 + w];
            float q = fminf(fmaxf(rintf(__fmul_rn(v, 128.f)), -128.f), 127.f);
            packed |= ((unsigned)(unsigned char)(signed char)(int)q) << (8 * k);
        }
        *(unsigned*)(tile + w * 272 + ci) = packed;
    }
    __syncthreads();
#pragma unroll
    for (int q = 0; q < 2; ++q) {
        const int wp = q * 16 + (t >> 4);
        const int ci16 = (t & 15) * 16;
        uint4 v = *(const uint4*)(tile + wp * 272 + ci16);
        *(uint4*)(rowbase + (size_t)(wp + 1) * 256 + ci16) = v;
    }
    if (t < 32) {
        const int wp = (t >> 4) * 33;
        *(uint4*)(rowbase + (size_t)wp * 256 + (t & 15) * 16) = z;
    }
}

// GEMM: grid 512 (256 m-tiles x 2 n-tiles), 512 threads = 8 waves (2m x 4n).
// Wave = 64m x 32n: 4 m-frags x 2 n-frags of 16x16x64 i8.
// LDS: A halo only, 6 rows x 34 wp x 256 ci = 52,224 B, xor-swizzled chunks.
__global__ __launch_bounds__(512, 4) void conv_gemm_kernel(
    const signed char* __restrict__ xpad, const signed char* __restrict__ wqm,
    const float* __restrict__ gamma, const float* __restrict__ beta,
    const float* __restrict__ mean, const float* __restrict__ var,
    float* __restrict__ out)
{
    __shared__ signed char As[6 * 34 * 256];   // [r=hh*34+wp][chunk ^ (r&15)][16]

    const int tid = threadIdx.x;
    const int wv = tid >> 6;
    const int lane = tid & 63;
    const int l16 = lane & 15;
    const int l4 = lane >> 4;

    const int mt = blockIdx.x >> 1;
    const int n0 = (blockIdx.x & 1) * 128;
    const int b = mt >> 3;
    const int h0 = (mt & 7) * 4;
    const int wave_m = wv & 1;    // 2 waves over m (64 each)
    const int wave_n = wv >> 1;   // 4 waves over n (32 each)

    // ---- stage A halo once: padded rows h0..h0+5, all 34 wp, all 256 ci ----
    const signed char* xbase = xpad + (size_t)(b * 34 + h0) * 34 * 256;
#pragma unroll
    for (int p = 0; p < 7; ++p) {                // 51 wave-shots x 1KB = 52,224B
        const int i = p * 8 + wv;
        if (i < 51) {
            const int d = i * 64 + lane;
            const int r = d >> 4;
            const int c = d & 15;
            gload_lds16(xbase + r * 256 + ((c ^ (r & 15)) << 4), As + i * 1024);
        }
    }
    __syncthreads();   // the ONLY barrier

    // per-frag A row bases: frag i -> h = h0+wave_m*2+(i>>1), w = (i&1)*16 + l16
    int r0[4];
#pragma unroll
    for (int i = 0; i < 4; ++i)
        r0[i] = (wave_m * 2 + (i >> 1)) * 34 + (i & 1) * 16 + l16;

    // B frag pointers (L2-hot, MFMA layout): frag j -> co_blk = n0/16 + wave_n*2 + j
    const signed char* bp0 = wqm + (((size_t)((n0 >> 4) + wave_n * 2 + 0) * 36) << 10) + lane * 16;
    const signed char* bp1 = wqm + (((size_t)((n0 >> 4) + wave_n * 2 + 1) * 36) << 10) + lane * 16;

    i32x4 acc[4][2];
#pragma unroll
    for (int i = 0; i < 4; i++)
#pragma unroll
        for (int j = 0; j < 2; j++) acc[i][j] = (i32x4){0, 0, 0, 0};

    i32x4 aP[2][4], bP[2][2];

#define LOAD_B(kt, dst) { dst[0] = *(const i32x4*)(bp0 + (kt) * 1024); \
                          dst[1] = *(const i32x4*)(bp1 + (kt) * 1024); }
#define LOAD_A(kt, dst) { const int khkw = (kt) >> 2; \
                          const int kh = khkw / 3; \
                          const int kw = khkw - 3 * kh; \
                          const int roff = kh * 34 + kw; \
                          const int cb = ((kt) & 3) * 4 + l4; \
                          _Pragma("unroll") \
                          for (int i = 0; i < 4; ++i) { \
                              const int r = r0[i] + roff; \
                              dst[i] = *(const i32x4*)(As + r * 256 + ((cb ^ (r & 15)) << 4)); \
                          } }
#define MFMA(af, bf) { _Pragma("unroll") \
                       for (int i = 0; i < 4; ++i) \
                           _Pragma("unroll") \
                           for (int j = 0; j < 2; ++j) \
                               acc[i][j] = __builtin_amdgcn_mfma_i32_16x16x64_i8(af[i], bf[j], acc[i][j], 0, 0, 0); }

    LOAD_B(0, bP[0])
    LOAD_A(0, aP[0])
#pragma unroll
    for (int kt = 0; kt < 36; ++kt) {            // FULL unroll: all offsets fold
        const int cur = kt & 1, nxt = cur ^ 1;
        if (kt + 1 < 36) { LOAD_B(kt + 1, bP[nxt]) LOAD_A(kt + 1, aP[nxt]) }
        MFMA(aP[cur], bP[cur])
    }

    // ---- epilogue: C/D col = l16 (n), row = l4*4 + r (m within frag) ----
#pragma unroll
    for (int j = 0; j < 2; ++j) {
        const int co = n0 + wave_n * 32 + j * 16 + l16;
        const float iv = __fdiv_rn(gamma[co], __fsqrt_rn(__fadd_rn(var[co], 1e-4f)));
        const float bias = __fsub_rn(beta[co], __fmul_rn(mean[co], iv));
#pragma unroll
        for (int i = 0; i < 4; ++i) {
            const int h = h0 + wave_m * 2 + (i >> 1);
            const int w = (i & 1) * 16 + l4 * 4;
            f32x4 v;
#pragma unroll
            for (int r = 0; r < 4; r++) {
                const float y = __fmul_rn((float)acc[i][j][r], 0.0078125f);  // exact pow2
                const float t = __fadd_rn(__fmul_rn(y, iv), bias);           // no FMA: match np
                float z = rintf(__fmul_rn(t, 2.f));
                z = fminf(fmaxf(z, -2.f), 1.f);
                v[r] = __fmul_rn(z, 0.5f);
            }
            *(f32x4*)(&out[(((size_t)(b * 256 + co)) * 32 + h) * 32 + w]) = v;
        }
    }
#undef LOAD_B
#undef LOAD_A
#undef MFMA
}

extern "C" void kernel_launch(void* const* d_in, const int* in_sizes, int n_in,
                              void* d_out, int out_size, void* d_ws, size_t ws_size,
                              hipStream_t stream) {
    const float* x      = (const float*)d_in[0];
    const float* weight = (const float*)d_in[1];
    const float* gamma  = (const float*)d_in[2];
    const float* beta   = (const float*)d_in[3];
    const float* rmean  = (const float*)d_in[4];
    const float* rvar   = (const float*)d_in[5];
    float* out = (float*)d_out;

    signed char* wq   = (signed char*)d_ws;                 // 589,824 B (MFMA layout)
    signed char* xpad = (signed char*)d_ws + (1 << 20);     // 9,469,952 B

    quant_w_kernel<<<256, 256, 0, stream>>>(weight, wq);
    quant_x_kernel<<<1088, 256, 0, stream>>>(x, xpad);
    conv_gemm_kernel<<<512, 512, 0, stream>>>(xpad, wq, gamma, beta, rmean, rvar, out);
}